// Round 2
// baseline (422.540 us; speedup 1.0000x reference)
//
#include <hip/hip_runtime.h>

// ---------------------------------------------------------------------------
// MultiHeadAttention: B=2, S=2048, E=1024, H=16, D=64, causal mask.
// R2: barrier-free flash attention. K loaded as native B-fragments from
// global; V pre-transposed to [B,H,D,S] by qkv_gemm epilogue so PV
// B-fragments load directly; only LDS use is the per-wave P C->A relayout
// (stride 68 -> conflict-free quad spread). Softmax in exp2 domain.
// ---------------------------------------------------------------------------

typedef __attribute__((ext_vector_type(8))) short short8;
typedef __attribute__((ext_vector_type(4))) float floatx4;

#define NB 2
#define SEQ 2048
#define EMB 1024
#define NH 16
#define HD 64
#define M_ROWS (NB * SEQ)        // 4096
#define N_QKV (3 * EMB)          // 3072

static __device__ __forceinline__ unsigned short f2bf(float f) {
    union { float f; unsigned int u; } v; v.f = f;
    unsigned int r = v.u + 0x7FFFu + ((v.u >> 16) & 1u);
    return (unsigned short)(r >> 16);
}
static __device__ __forceinline__ float bf2f(unsigned short h) {
    union { unsigned int u; float f; } v; v.u = ((unsigned int)h) << 16;
    return v.f;
}

// ---------------------------------------------------------------------------
// Dtype detection (bf16 vs fp32 delivery) — see R0 notes. flag=1 -> bf16.
// ---------------------------------------------------------------------------
__global__ void detect_dtype(const unsigned short* __restrict__ x, int* __restrict__ flag) {
    __shared__ int sh[256];
    int t = threadIdx.x;
    int cnt = 0;
    for (int i = 0; i < 16; ++i) {
        unsigned short u = x[(t * 16 + i) * 2];
        int e = (u >> 7) & 0xFF;
        if (e >= 112 && e <= 134) cnt++;
    }
    sh[t] = cnt;
    __syncthreads();
    for (int s = 128; s > 0; s >>= 1) {
        if (t < s) sh[t] += sh[t + s];
        __syncthreads();
    }
    if (t == 0) flag[0] = (sh[0] > 2048) ? 1 : 0;
}

__global__ void norm_to_bf16(const void* __restrict__ in, unsigned short* __restrict__ out,
                             int n4, const int* __restrict__ flag) {
    int i = blockIdx.x * blockDim.x + threadIdx.x;
    if (i >= n4) return;
    if (*flag) {
        ((unsigned long long*)out)[i] = ((const unsigned long long*)in)[i];
    } else {
        float4 v = ((const float4*)in)[i];
        unsigned long long p = (unsigned long long)f2bf(v.x)
            | ((unsigned long long)f2bf(v.y) << 16)
            | ((unsigned long long)f2bf(v.z) << 32)
            | ((unsigned long long)f2bf(v.w) << 48);
        ((unsigned long long*)out)[i] = p;
    }
}

__global__ void transpose_to_bf16(const void* __restrict__ in, unsigned short* __restrict__ out,
                                  int R, int C, const int* __restrict__ flag) {
    __shared__ unsigned short tile[32][33];
    int tx = threadIdx.x, ty = threadIdx.y;
    int c0 = blockIdx.x * 32, r0 = blockIdx.y * 32;
    bool isbf = (*flag != 0);
    #pragma unroll
    for (int j = 0; j < 4; ++j) {
        int r = r0 + ty + j * 8, c = c0 + tx;
        unsigned short v = isbf ? ((const unsigned short*)in)[(size_t)r * C + c]
                                : f2bf(((const float*)in)[(size_t)r * C + c]);
        tile[ty + j * 8][tx] = v;
    }
    __syncthreads();
    #pragma unroll
    for (int j = 0; j < 4; ++j)
        out[(size_t)(c0 + ty + j * 8) * R + r0 + tx] = tile[tx][ty + j * 8];
}

__global__ void norm_bias_f32(const void* __restrict__ in, float* __restrict__ out,
                              int n, const int* __restrict__ flag) {
    int i = blockIdx.x * blockDim.x + threadIdx.x;
    if (i >= n) return;
    out[i] = (*flag) ? bf2f(((const unsigned short*)in)[i]) : ((const float*)in)[i];
}

// ---------------------------------------------------------------------------
// QKV GEMM: 128x128 tile, BK=32. Q,K scattered to [B,H,S,D]; V scattered
// TRANSPOSED to [B,H,D,S] (4 row-values contiguous -> packed 8B stores).
// ---------------------------------------------------------------------------
#define LDT 40

__global__ __launch_bounds__(256) void qkv_gemm(
    const unsigned short* __restrict__ A,   // [4096][1024]
    const unsigned short* __restrict__ Bt,  // [3072][1024]  (W_qkv^T)
    const float* __restrict__ bias,         // [3072]
    unsigned short* __restrict__ qb, unsigned short* __restrict__ kb,
    unsigned short* __restrict__ vb)        // vb: [B,H,D,S]
{
    const int K = EMB;
    __shared__ __align__(16) unsigned short As[128 * LDT];
    __shared__ __align__(16) unsigned short Bs[128 * LDT];
    int t = threadIdx.x;
    int m0 = blockIdx.y * 128;
    int n0 = blockIdx.x * 128;
    int w = t >> 6, lane = t & 63, quad = lane >> 4, lcol = lane & 15;
    int wr = w >> 1, wc = w & 1;

    floatx4 zero = {0.f, 0.f, 0.f, 0.f};
    floatx4 acc[4][4];
    #pragma unroll
    for (int i = 0; i < 4; ++i)
        #pragma unroll
        for (int j = 0; j < 4; ++j) acc[i][j] = zero;

    int sr = t >> 1;
    int sc = (t & 1) << 4;
    const unsigned short* aG = A + (size_t)(m0 + sr) * K + sc;
    const unsigned short* bG = Bt + (size_t)(n0 + sr) * K + sc;

    for (int k0 = 0; k0 < K; k0 += 32) {
        __syncthreads();
        *(int4*)(&As[sr * LDT + sc])     = *(const int4*)(aG + k0);
        *(int4*)(&As[sr * LDT + sc + 8]) = *(const int4*)(aG + k0 + 8);
        *(int4*)(&Bs[sr * LDT + sc])     = *(const int4*)(bG + k0);
        *(int4*)(&Bs[sr * LDT + sc + 8]) = *(const int4*)(bG + k0 + 8);
        __syncthreads();
        short8 af[4], bfm[4];
        #pragma unroll
        for (int i = 0; i < 4; ++i)
            af[i] = *(const short8*)(&As[(wr * 64 + i * 16 + lcol) * LDT + quad * 8]);
        #pragma unroll
        for (int j = 0; j < 4; ++j)
            bfm[j] = *(const short8*)(&Bs[(wc * 64 + j * 16 + lcol) * LDT + quad * 8]);
        #pragma unroll
        for (int i = 0; i < 4; ++i)
            #pragma unroll
            for (int j = 0; j < 4; ++j)
                acc[i][j] = __builtin_amdgcn_mfma_f32_16x16x32_bf16(af[i], bfm[j], acc[i][j], 0, 0, 0);
    }

    #pragma unroll
    for (int i = 0; i < 4; ++i) {
        int m = m0 + wr * 64 + i * 16 + quad * 4;
        int b = m >> 11, s = m & 2047;
        #pragma unroll
        for (int j = 0; j < 4; ++j) {
            int n = n0 + wc * 64 + j * 16 + lcol;
            int which = n >> 10;
            int e = n & 1023;
            int h = e >> 6, d = e & 63;
            float bv = bias[n];
            if (which == 2) {
                // V: [b][h][d][s], 4 consecutive tokens -> one 8B store
                size_t base = ((size_t)((b * NH + h) * HD + d)) * SEQ + s;
                unsigned long long pk = (unsigned long long)f2bf(acc[i][j][0] + bv)
                    | ((unsigned long long)f2bf(acc[i][j][1] + bv) << 16)
                    | ((unsigned long long)f2bf(acc[i][j][2] + bv) << 32)
                    | ((unsigned long long)f2bf(acc[i][j][3] + bv) << 48);
                *(unsigned long long*)(&vb[base]) = pk;
            } else {
                unsigned short* dst = (which == 0) ? qb : kb;
                size_t base = ((size_t)((b * NH + h) * SEQ + s)) * HD + d;
                #pragma unroll
                for (int r = 0; r < 4; ++r)
                    dst[base + (size_t)r * HD] = f2bf(acc[i][j][r] + bv);
            }
        }
    }
}

// ---------------------------------------------------------------------------
// Flash attention, causal, barrier-free. Block = 4 waves; wave w owns query
// strip q0+16w..+15. K/Q/V fragments loaded directly from global (dwordx4).
// Only LDS: per-wave P relayout, stride 68 (quads hit banks {0,8,16,24}).
// ---------------------------------------------------------------------------
#define PST 68

__global__ __launch_bounds__(256) void attn_kernel(
    const unsigned short* __restrict__ Q,   // [B*H][S][D]
    const unsigned short* __restrict__ Kk,  // [B*H][S][D]
    const unsigned short* __restrict__ Vt,  // [B*H][D][S]
    unsigned short* __restrict__ Out)       // [b][s][h*64+d]
{
    __shared__ __align__(16) unsigned short Ps[4][16 * PST];

    int qt = blockIdx.x;
    int bh = blockIdx.y;
    int q0 = qt * 64;
    int t = threadIdx.x;
    int w = t >> 6, lane = t & 63, quad = lane >> 4, lcol = lane & 15;
    const size_t hoff = (size_t)bh * SEQ * HD;

    // Q strip fragments (A-operand): rows q0+16w+lcol, k = quad*8..(+8), +32
    const unsigned short* qptr = Q + hoff + (size_t)(q0 + 16 * w + lcol) * HD + quad * 8;
    short8 aq0 = *(const short8*)qptr;
    short8 aq1 = *(const short8*)(qptr + 32);

    floatx4 zero = {0.f, 0.f, 0.f, 0.f};
    float m_i[4], l_i[4];
    floatx4 O[4];
    #pragma unroll
    for (int r = 0; r < 4; ++r) { m_i[r] = -3.0e38f; l_i[r] = 0.f; }
    #pragma unroll
    for (int d = 0; d < 4; ++d) O[d] = zero;

    const float SC = 0.18033688011112043f;  // (1/sqrt(64)) * log2(e)

    const unsigned short* kbase0 = Kk + hoff + (size_t)lcol * HD + quad * 8;
    const unsigned short* vbase0 = Vt + hoff + (size_t)lcol * SEQ + quad * 8;

    for (int kt = 0; kt <= qt; ++kt) {
        int k0 = kt * 64;
        // ---- K fragments (B-operand, native layout) ----
        const unsigned short* kb_ = kbase0 + (size_t)k0 * HD;
        short8 bk[4][2];
        #pragma unroll
        for (int tc = 0; tc < 4; ++tc) {
            bk[tc][0] = *(const short8*)(kb_ + (size_t)tc * 16 * HD);
            bk[tc][1] = *(const short8*)(kb_ + (size_t)tc * 16 * HD + 32);
        }
        // ---- S = Q K^T ----
        floatx4 sacc[4];
        #pragma unroll
        for (int tc = 0; tc < 4; ++tc) {
            sacc[tc] = __builtin_amdgcn_mfma_f32_16x16x32_bf16(aq0, bk[tc][0], zero, 0, 0, 0);
            sacc[tc] = __builtin_amdgcn_mfma_f32_16x16x32_bf16(aq1, bk[tc][1], sacc[tc], 0, 0, 0);
        }
        // ---- V fragments (B-operand from pre-transposed V) ----
        const unsigned short* vb_ = vbase0 + k0;
        short8 bv[4][2];
        #pragma unroll
        for (int td = 0; td < 4; ++td) {
            bv[td][0] = *(const short8*)(vb_ + (size_t)td * 16 * SEQ);
            bv[td][1] = *(const short8*)(vb_ + (size_t)td * 16 * SEQ + 32);
        }

        // ---- scale + causal mask (exp2 domain) ----
        bool diag = (kt == qt);
        #pragma unroll
        for (int tc = 0; tc < 4; ++tc) {
            int key = k0 + tc * 16 + lcol;
            #pragma unroll
            for (int r = 0; r < 4; ++r) {
                float s = sacc[tc][r] * SC;
                if (diag) {
                    int qrow = q0 + 16 * w + quad * 4 + r;
                    if (key > qrow) s = -3.0e38f;
                }
                sacc[tc][r] = s;
            }
        }
        // ---- row max across 16 lanes of the quad ----
        float mloc[4];
        #pragma unroll
        for (int r = 0; r < 4; ++r)
            mloc[r] = fmaxf(fmaxf(sacc[0][r], sacc[1][r]), fmaxf(sacc[2][r], sacc[3][r]));
        #pragma unroll
        for (int r = 0; r < 4; ++r) {
            #pragma unroll
            for (int off = 1; off < 16; off <<= 1)
                mloc[r] = fmaxf(mloc[r], __shfl_xor(mloc[r], off, 64));
        }
        float alpha[4], psum[4];
        #pragma unroll
        for (int r = 0; r < 4; ++r) {
            float mn = fmaxf(m_i[r], mloc[r]);
            alpha[r] = __builtin_amdgcn_exp2f(m_i[r] - mn);
            m_i[r] = mn;
            psum[r] = 0.f;
        }
        // ---- P = exp2(s - m), write to per-wave LDS in C-layout ----
        #pragma unroll
        for (int tc = 0; tc < 4; ++tc) {
            #pragma unroll
            for (int r = 0; r < 4; ++r) {
                float p = __builtin_amdgcn_exp2f(sacc[tc][r] - m_i[r]);
                psum[r] += p;
                Ps[w][(quad * 4 + r) * PST + tc * 16 + lcol] = f2bf(p);
            }
        }
        #pragma unroll
        for (int r = 0; r < 4; ++r) {
            #pragma unroll
            for (int off = 1; off < 16; off <<= 1)
                psum[r] += __shfl_xor(psum[r], off, 64);
            l_i[r] = l_i[r] * alpha[r] + psum[r];
        }
        #pragma unroll
        for (int td = 0; td < 4; ++td) {
            #pragma unroll
            for (int r = 0; r < 4; ++r) O[td][r] *= alpha[r];
        }
        // ---- O += P @ V ----
        short8 ap0 = *(const short8*)(&Ps[w][lcol * PST + quad * 8]);
        short8 ap1 = *(const short8*)(&Ps[w][lcol * PST + 32 + quad * 8]);
        #pragma unroll
        for (int td = 0; td < 4; ++td) {
            O[td] = __builtin_amdgcn_mfma_f32_16x16x32_bf16(ap0, bv[td][0], O[td], 0, 0, 0);
            O[td] = __builtin_amdgcn_mfma_f32_16x16x32_bf16(ap1, bv[td][1], O[td], 0, 0, 0);
        }
    }

    int b = bh >> 4, h = bh & 15;
    float inv[4];
    #pragma unroll
    for (int r = 0; r < 4; ++r) inv[r] = 1.0f / l_i[r];
    size_t obase = ((size_t)b * SEQ) * EMB + (size_t)h * HD;
    #pragma unroll
    for (int td = 0; td < 4; ++td) {
        #pragma unroll
        for (int r = 0; r < 4; ++r) {
            int qrow = q0 + 16 * w + quad * 4 + r;
            Out[obase + (size_t)qrow * EMB + td * 16 + lcol] = f2bf(O[td][r] * inv[r]);
        }
    }
}

// ---------------------------------------------------------------------------
// Output projection: out[4096][1024] = attn @ W_o + b_o (fp32 or bf16 store)
// ---------------------------------------------------------------------------
__global__ __launch_bounds__(256) void oproj_gemm(
    const unsigned short* __restrict__ A,   // [4096][1024]
    const unsigned short* __restrict__ Bt,  // [1024][1024]  (W_o^T)
    const float* __restrict__ bias,         // [1024]
    void* __restrict__ Cout,
    const int* __restrict__ flag)
{
    const int K = EMB;
    __shared__ __align__(16) unsigned short As[128 * LDT];
    __shared__ __align__(16) unsigned short Bs[128 * LDT];
    int t = threadIdx.x;
    int m0 = blockIdx.y * 128;
    int n0 = blockIdx.x * 128;
    int w = t >> 6, lane = t & 63, quad = lane >> 4, lcol = lane & 15;
    int wr = w >> 1, wc = w & 1;

    floatx4 zero = {0.f, 0.f, 0.f, 0.f};
    floatx4 acc[4][4];
    #pragma unroll
    for (int i = 0; i < 4; ++i)
        #pragma unroll
        for (int j = 0; j < 4; ++j) acc[i][j] = zero;

    int sr = t >> 1;
    int sc = (t & 1) << 4;
    const unsigned short* aG = A + (size_t)(m0 + sr) * K + sc;
    const unsigned short* bG = Bt + (size_t)(n0 + sr) * K + sc;

    for (int k0 = 0; k0 < K; k0 += 32) {
        __syncthreads();
        *(int4*)(&As[sr * LDT + sc])     = *(const int4*)(aG + k0);
        *(int4*)(&As[sr * LDT + sc + 8]) = *(const int4*)(aG + k0 + 8);
        *(int4*)(&Bs[sr * LDT + sc])     = *(const int4*)(bG + k0);
        *(int4*)(&Bs[sr * LDT + sc + 8]) = *(const int4*)(bG + k0 + 8);
        __syncthreads();
        short8 af[4], bfm[4];
        #pragma unroll
        for (int i = 0; i < 4; ++i)
            af[i] = *(const short8*)(&As[(wr * 64 + i * 16 + lcol) * LDT + quad * 8]);
        #pragma unroll
        for (int j = 0; j < 4; ++j)
            bfm[j] = *(const short8*)(&Bs[(wc * 64 + j * 16 + lcol) * LDT + quad * 8]);
        #pragma unroll
        for (int i = 0; i < 4; ++i)
            #pragma unroll
            for (int j = 0; j < 4; ++j)
                acc[i][j] = __builtin_amdgcn_mfma_f32_16x16x32_bf16(af[i], bfm[j], acc[i][j], 0, 0, 0);
    }

    bool isbf = (*flag != 0);
    #pragma unroll
    for (int i = 0; i < 4; ++i) {
        int m = m0 + wr * 64 + i * 16 + quad * 4;
        #pragma unroll
        for (int j = 0; j < 4; ++j) {
            int n = n0 + wc * 64 + j * 16 + lcol;
            float bv = bias[n];
            #pragma unroll
            for (int r = 0; r < 4; ++r) {
                float v = acc[i][j][r] + bv;
                size_t idx = (size_t)(m + r) * EMB + n;
                if (isbf) ((unsigned short*)Cout)[idx] = f2bf(v);
                else      ((float*)Cout)[idx] = v;
            }
        }
    }
}

// ---------------------------------------------------------------------------
extern "C" void kernel_launch(void* const* d_in, const int* in_sizes, int n_in,
                              void* d_out, int out_size, void* d_ws, size_t ws_size,
                              hipStream_t stream) {
    (void)in_sizes; (void)n_in; (void)out_size; (void)ws_size;
    char* ws = (char*)d_ws;
    const size_t OFF_X     = 1024;
    const size_t OFF_WQKVT = OFF_X     + (size_t)M_ROWS * EMB * 2;
    const size_t OFF_WOT   = OFF_WQKVT + (size_t)N_QKV * EMB * 2;
    const size_t OFF_BQKV  = OFF_WOT   + (size_t)EMB * EMB * 2;
    const size_t OFF_BO    = OFF_BQKV  + 16384;
    const size_t OFF_Q     = OFF_BO    + 16384;
    const size_t OFF_K     = OFF_Q     + (size_t)M_ROWS * EMB * 2;
    const size_t OFF_V     = OFF_K     + (size_t)M_ROWS * EMB * 2;
    const size_t OFF_ATTN  = OFF_V     + (size_t)M_ROWS * EMB * 2;

    int* flag = (int*)ws;
    unsigned short* x_bf   = (unsigned short*)(ws + OFF_X);
    unsigned short* wqkvT  = (unsigned short*)(ws + OFF_WQKVT);
    unsigned short* woT    = (unsigned short*)(ws + OFF_WOT);
    float*          bqkv_f = (float*)(ws + OFF_BQKV);
    float*          bo_f   = (float*)(ws + OFF_BO);
    unsigned short* qb     = (unsigned short*)(ws + OFF_Q);
    unsigned short* kb     = (unsigned short*)(ws + OFF_K);
    unsigned short* vb     = (unsigned short*)(ws + OFF_V);   // [B,H,D,S]
    unsigned short* attn   = (unsigned short*)(ws + OFF_ATTN);

    detect_dtype<<<1, 256, 0, stream>>>((const unsigned short*)d_in[0], flag);
    norm_to_bf16<<<(M_ROWS * EMB / 4 + 255) / 256, 256, 0, stream>>>(d_in[0], x_bf, M_ROWS * EMB / 4, flag);
    transpose_to_bf16<<<dim3(N_QKV / 32, EMB / 32), dim3(32, 8), 0, stream>>>(d_in[1], wqkvT, EMB, N_QKV, flag);
    transpose_to_bf16<<<dim3(EMB / 32, EMB / 32), dim3(32, 8), 0, stream>>>(d_in[3], woT, EMB, EMB, flag);
    norm_bias_f32<<<(N_QKV + 255) / 256, 256, 0, stream>>>(d_in[2], bqkv_f, N_QKV, flag);
    norm_bias_f32<<<(EMB + 255) / 256, 256, 0, stream>>>(d_in[4], bo_f, EMB, flag);

    qkv_gemm<<<dim3(N_QKV / 128, M_ROWS / 128), 256, 0, stream>>>(x_bf, wqkvT, bqkv_f, qb, kb, vb);
    attn_kernel<<<dim3(SEQ / 64, NB * NH), 256, 0, stream>>>(qb, kb, vb, attn);
    oproj_gemm<<<dim3(EMB / 128, M_ROWS / 128), 256, 0, stream>>>(attn, woT, bo_f, d_out, flag);
}

// Round 5
// 263.710 us; speedup vs baseline: 1.6023x; 1.6023x over previous
//
#include <hip/hip_runtime.h>

// ---------------------------------------------------------------------------
// MultiHeadAttention: B=2, S=2048, E=1024, H=16, D=64, causal.
// R4: == R3b structure, fp32 I/O restored (R3b's NaN proved harness delivers
// fp32; R1/R2 passed via the flag=0 fp32 paths). Internals bf16 MFMA.
// Attention: LDS-staged flash, fixed softmax base (m=0), single barrier per
// K-tile, post-barrier prefetch, pre-transposed V, paired q-tiles (z, 31-z).
// ---------------------------------------------------------------------------

typedef __attribute__((ext_vector_type(8))) short short8;
typedef __attribute__((ext_vector_type(4))) float floatx4;

#define NB 2
#define SEQ 2048
#define EMB 1024
#define NH 16
#define HD 64
#define M_ROWS (NB * SEQ)        // 4096
#define N_QKV (3 * EMB)          // 3072

static __device__ __forceinline__ unsigned short f2bf(float f) {
    union { float f; unsigned int u; } v; v.f = f;
    unsigned int r = v.u + 0x7FFFu + ((v.u >> 16) & 1u);
    return (unsigned short)(r >> 16);
}

// x fp32 -> bf16 (4 elems / thread)
__global__ void x_to_bf16(const float* __restrict__ in, unsigned short* __restrict__ out, int n4) {
    int i = blockIdx.x * blockDim.x + threadIdx.x;
    if (i >= n4) return;
    float4 v = ((const float4*)in)[i];
    unsigned long long p = (unsigned long long)f2bf(v.x)
        | ((unsigned long long)f2bf(v.y) << 16)
        | ((unsigned long long)f2bf(v.z) << 32)
        | ((unsigned long long)f2bf(v.w) << 48);
    ((unsigned long long*)out)[i] = p;
}

// W[R][C] fp32 -> Wt[C][R] bf16
__global__ void transpose_f32_bf16(const float* __restrict__ in,
                                   unsigned short* __restrict__ out, int R, int C) {
    __shared__ unsigned short tile[32][33];
    int tx = threadIdx.x, ty = threadIdx.y;
    int c0 = blockIdx.x * 32, r0 = blockIdx.y * 32;
    #pragma unroll
    for (int j = 0; j < 4; ++j)
        tile[ty + j * 8][tx] = f2bf(in[(size_t)(r0 + ty + j * 8) * C + c0 + tx]);
    __syncthreads();
    #pragma unroll
    for (int j = 0; j < 4; ++j)
        out[(size_t)(c0 + ty + j * 8) * R + r0 + tx] = tile[tx][ty + j * 8];
}

// ---------------------------------------------------------------------------
// QKV GEMM: 128x128 tile, BK=32. Q,K -> [B,H,S,D]; V -> [B,H,D,S] (transposed,
// 4 consecutive tokens -> one 8B store). bias fp32.
// ---------------------------------------------------------------------------
#define LDT 40

__global__ __launch_bounds__(256) void qkv_gemm(
    const unsigned short* __restrict__ A,    // x_bf [4096][1024]
    const unsigned short* __restrict__ Bt,   // W_qkv^T [3072][1024] bf16
    const float* __restrict__ bias,          // [3072] fp32
    unsigned short* __restrict__ qb, unsigned short* __restrict__ kb,
    unsigned short* __restrict__ vb)         // vb: [B,H,D,S]
{
    const int K = EMB;
    __shared__ __align__(16) unsigned short As[128 * LDT];
    __shared__ __align__(16) unsigned short Bs[128 * LDT];
    int t = threadIdx.x;
    int m0 = blockIdx.y * 128;
    int n0 = blockIdx.x * 128;
    int w = t >> 6, lane = t & 63, quad = lane >> 4, lcol = lane & 15;
    int wr = w >> 1, wc = w & 1;

    floatx4 zero = {0.f, 0.f, 0.f, 0.f};
    floatx4 acc[4][4];
    #pragma unroll
    for (int i = 0; i < 4; ++i)
        #pragma unroll
        for (int j = 0; j < 4; ++j) acc[i][j] = zero;

    int sr = t >> 1;
    int sc = (t & 1) << 4;
    const unsigned short* aG = A + (size_t)(m0 + sr) * K + sc;
    const unsigned short* bG = Bt + (size_t)(n0 + sr) * K + sc;

    for (int k0 = 0; k0 < K; k0 += 32) {
        __syncthreads();
        *(int4*)(&As[sr * LDT + sc])     = *(const int4*)(aG + k0);
        *(int4*)(&As[sr * LDT + sc + 8]) = *(const int4*)(aG + k0 + 8);
        *(int4*)(&Bs[sr * LDT + sc])     = *(const int4*)(bG + k0);
        *(int4*)(&Bs[sr * LDT + sc + 8]) = *(const int4*)(bG + k0 + 8);
        __syncthreads();
        short8 af[4], bfm[4];
        #pragma unroll
        for (int i = 0; i < 4; ++i)
            af[i] = *(const short8*)(&As[(wr * 64 + i * 16 + lcol) * LDT + quad * 8]);
        #pragma unroll
        for (int j = 0; j < 4; ++j)
            bfm[j] = *(const short8*)(&Bs[(wc * 64 + j * 16 + lcol) * LDT + quad * 8]);
        #pragma unroll
        for (int i = 0; i < 4; ++i)
            #pragma unroll
            for (int j = 0; j < 4; ++j)
                acc[i][j] = __builtin_amdgcn_mfma_f32_16x16x32_bf16(af[i], bfm[j], acc[i][j], 0, 0, 0);
    }

    #pragma unroll
    for (int i = 0; i < 4; ++i) {
        int m = m0 + wr * 64 + i * 16 + quad * 4;
        int b = m >> 11, s = m & 2047;
        #pragma unroll
        for (int j = 0; j < 4; ++j) {
            int n = n0 + wc * 64 + j * 16 + lcol;
            int which = n >> 10;
            int e = n & 1023;
            int h = e >> 6, d = e & 63;
            float bv = bias[n];
            if (which == 2) {
                size_t base = ((size_t)((b * NH + h) * HD + d)) * SEQ + s;
                unsigned long long pk = (unsigned long long)f2bf(acc[i][j][0] + bv)
                    | ((unsigned long long)f2bf(acc[i][j][1] + bv) << 16)
                    | ((unsigned long long)f2bf(acc[i][j][2] + bv) << 32)
                    | ((unsigned long long)f2bf(acc[i][j][3] + bv) << 48);
                *(unsigned long long*)(&vb[base]) = pk;
            } else {
                unsigned short* dst = (which == 0) ? qb : kb;
                size_t base = ((size_t)((b * NH + h) * SEQ + s)) * HD + d;
                #pragma unroll
                for (int r = 0; r < 4; ++r)
                    dst[base + (size_t)r * HD] = f2bf(acc[i][j][r] + bv);
            }
        }
    }
}

// ---------------------------------------------------------------------------
// Flash attention, causal, fixed softmax base. Block z handles q-tiles
// qtA = z, qtB = 31 - z (33 tile-computes each). 4 waves x 16 query rows per
// strip. One barrier per K-tile; global prefetch issued after the barrier.
// ---------------------------------------------------------------------------
#define KST 72
#define PST 68

__global__ __launch_bounds__(256, 2) void attn_kernel(
    const unsigned short* __restrict__ Q,   // [B*H][S][D]
    const unsigned short* __restrict__ Kk,  // [B*H][S][D]
    const unsigned short* __restrict__ Vt,  // [B*H][D][S]
    unsigned short* __restrict__ Out)       // [b][s][h*64+d]
{
    __shared__ __align__(16) unsigned short Ks[2][64 * KST];
    __shared__ __align__(16) unsigned short Vs[2][64 * KST];
    __shared__ __align__(16) unsigned short Ps[4][2][16 * PST];

    int z = blockIdx.x;              // 0..15
    int bh = blockIdx.y;
    int qtA = z, qtB = 31 - z;
    int t = threadIdx.x;
    int w = t >> 6, lane = t & 63, quad = lane >> 4, lcol = lane & 15;
    const size_t hoff = (size_t)bh * SEQ * HD;
    const float SC = 0.18033688011112043f;   // (1/sqrt(64)) * log2(e)

    // Q fragments for both strips (A-operand, native layout)
    const unsigned short* qpA = Q + hoff + (size_t)(qtA * 64 + 16 * w + lcol) * HD + quad * 8;
    const unsigned short* qpB = Q + hoff + (size_t)(qtB * 64 + 16 * w + lcol) * HD + quad * 8;
    short8 aqA0 = *(const short8*)qpA, aqA1 = *(const short8*)(qpA + 32);
    short8 aqB0 = *(const short8*)qpB, aqB1 = *(const short8*)(qpB + 32);

    // staging map: thread t -> tile row t>>2, 32B chunk (t&3)*16 shorts
    int srow = t >> 2;
    int sseg = (t & 3) << 4;
    const unsigned short* kgl = Kk + hoff + (size_t)srow * HD + sseg;   // + kt*64*HD
    const unsigned short* vgl = Vt + hoff + (size_t)srow * SEQ + sseg;  // + kt*64
    unsigned short* ksw = &Ks[0][srow * KST + sseg];
    unsigned short* vsw = &Vs[0][srow * KST + sseg];
    const int bufStride = 64 * KST;

    floatx4 zero = {0.f, 0.f, 0.f, 0.f};
    floatx4 OA[4], OB[4];
    float lA[4], lB[4];
    #pragma unroll
    for (int r = 0; r < 4; ++r) { lA[r] = 0.f; lB[r] = 0.f; }
    #pragma unroll
    for (int d = 0; d < 4; ++d) { OA[d] = zero; OB[d] = zero; }

    int4 kv[2][4];
    kv[0][0] = *(const int4*)(kgl);
    kv[0][1] = *(const int4*)(kgl + 8);
    kv[0][2] = *(const int4*)(vgl);
    kv[0][3] = *(const int4*)(vgl + 8);

    const int nkt = qtB + 1;
    for (int kt = 0; kt < nkt; ++kt) {
        int cur = kt & 1, nxt = cur ^ 1;
        *(int4*)(ksw + cur * bufStride)     = kv[cur][0];
        *(int4*)(ksw + cur * bufStride + 8) = kv[cur][1];
        *(int4*)(vsw + cur * bufStride)     = kv[cur][2];
        *(int4*)(vsw + cur * bufStride + 8) = kv[cur][3];
        __syncthreads();
        if (kt + 1 < nkt) {
            const unsigned short* kg = kgl + (size_t)(kt + 1) * 64 * HD;
            const unsigned short* vg = vgl + (kt + 1) * 64;
            kv[nxt][0] = *(const int4*)(kg);
            kv[nxt][1] = *(const int4*)(kg + 8);
            kv[nxt][2] = *(const int4*)(vg);
            kv[nxt][3] = *(const int4*)(vg + 8);
        }

        const unsigned short* ksr = &Ks[cur][0];
        const unsigned short* vsr = &Vs[cur][0];
        short8 bk0[4], bk1[4], bv0[4], bv1[4];
        #pragma unroll
        for (int tc = 0; tc < 4; ++tc) {
            bk0[tc] = *(const short8*)(ksr + (tc * 16 + lcol) * KST + quad * 8);
            bk1[tc] = *(const short8*)(ksr + (tc * 16 + lcol) * KST + 32 + quad * 8);
            bv0[tc] = *(const short8*)(vsr + (tc * 16 + lcol) * KST + quad * 8);
            bv1[tc] = *(const short8*)(vsr + (tc * 16 + lcol) * KST + 32 + quad * 8);
        }

        // ---- strip B (always active: kt <= qtB) ----
        {
            floatx4 sacc[4];
            #pragma unroll
            for (int tc = 0; tc < 4; ++tc) {
                sacc[tc] = __builtin_amdgcn_mfma_f32_16x16x32_bf16(aqB0, bk0[tc], zero, 0, 0, 0);
                sacc[tc] = __builtin_amdgcn_mfma_f32_16x16x32_bf16(aqB1, bk1[tc], sacc[tc], 0, 0, 0);
            }
            bool diag = (kt == qtB);
            unsigned short* PsW = &Ps[w][1][0];
            int rbase = 16 * w + quad * 4;
            #pragma unroll
            for (int tc = 0; tc < 4; ++tc) {
                int keyc = tc * 16 + lcol;
                #pragma unroll
                for (int r = 0; r < 4; ++r) {
                    float p = __builtin_amdgcn_exp2f(sacc[tc][r] * SC);
                    if (diag && keyc > rbase + r) p = 0.f;
                    lB[r] += p;
                    PsW[(quad * 4 + r) * PST + keyc] = f2bf(p);
                }
            }
            short8 ap0 = *(const short8*)(&PsW[lcol * PST + quad * 8]);
            short8 ap1 = *(const short8*)(&PsW[lcol * PST + 32 + quad * 8]);
            #pragma unroll
            for (int td = 0; td < 4; ++td) {
                OB[td] = __builtin_amdgcn_mfma_f32_16x16x32_bf16(ap0, bv0[td], OB[td], 0, 0, 0);
                OB[td] = __builtin_amdgcn_mfma_f32_16x16x32_bf16(ap1, bv1[td], OB[td], 0, 0, 0);
            }
        }
        // ---- strip A (active while kt <= qtA) ----
        if (kt <= qtA) {
            floatx4 sacc[4];
            #pragma unroll
            for (int tc = 0; tc < 4; ++tc) {
                sacc[tc] = __builtin_amdgcn_mfma_f32_16x16x32_bf16(aqA0, bk0[tc], zero, 0, 0, 0);
                sacc[tc] = __builtin_amdgcn_mfma_f32_16x16x32_bf16(aqA1, bk1[tc], sacc[tc], 0, 0, 0);
            }
            bool diag = (kt == qtA);
            unsigned short* PsW = &Ps[w][0][0];
            int rbase = 16 * w + quad * 4;
            #pragma unroll
            for (int tc = 0; tc < 4; ++tc) {
                int keyc = tc * 16 + lcol;
                #pragma unroll
                for (int r = 0; r < 4; ++r) {
                    float p = __builtin_amdgcn_exp2f(sacc[tc][r] * SC);
                    if (diag && keyc > rbase + r) p = 0.f;
                    lA[r] += p;
                    PsW[(quad * 4 + r) * PST + keyc] = f2bf(p);
                }
            }
            short8 ap0 = *(const short8*)(&PsW[lcol * PST + quad * 8]);
            short8 ap1 = *(const short8*)(&PsW[lcol * PST + 32 + quad * 8]);
            #pragma unroll
            for (int td = 0; td < 4; ++td) {
                OA[td] = __builtin_amdgcn_mfma_f32_16x16x32_bf16(ap0, bv0[td], OA[td], 0, 0, 0);
                OA[td] = __builtin_amdgcn_mfma_f32_16x16x32_bf16(ap1, bv1[td], OA[td], 0, 0, 0);
            }
        }
    }

    int b = bh >> 4, h = bh & 15;
    size_t obase = ((size_t)b * SEQ) * EMB + (size_t)h * HD;
    #pragma unroll
    for (int r = 0; r < 4; ++r) {
        #pragma unroll
        for (int off = 1; off < 16; off <<= 1) {
            lA[r] += __shfl_xor(lA[r], off, 64);
            lB[r] += __shfl_xor(lB[r], off, 64);
        }
        lA[r] = 1.0f / lA[r];
        lB[r] = 1.0f / lB[r];
    }
    #pragma unroll
    for (int td = 0; td < 4; ++td) {
        #pragma unroll
        for (int r = 0; r < 4; ++r) {
            int rowA = qtA * 64 + 16 * w + quad * 4 + r;
            int rowB = qtB * 64 + 16 * w + quad * 4 + r;
            Out[obase + (size_t)rowA * EMB + td * 16 + lcol] = f2bf(OA[td][r] * lA[r]);
            Out[obase + (size_t)rowB * EMB + td * 16 + lcol] = f2bf(OB[td][r] * lB[r]);
        }
    }
}

// ---------------------------------------------------------------------------
// Output projection: out[4096][1024] = attn @ W_o + b_o. fp32 bias, fp32 out.
// ---------------------------------------------------------------------------
__global__ __launch_bounds__(256) void oproj_gemm(
    const unsigned short* __restrict__ A,    // [4096][1024] bf16
    const unsigned short* __restrict__ Bt,   // W_o^T [1024][1024] bf16
    const float* __restrict__ bias,          // [1024] fp32
    float* __restrict__ Cout)                // [4096][1024] fp32
{
    const int K = EMB;
    __shared__ __align__(16) unsigned short As[128 * LDT];
    __shared__ __align__(16) unsigned short Bs[128 * LDT];
    int t = threadIdx.x;
    int m0 = blockIdx.y * 128;
    int n0 = blockIdx.x * 128;
    int w = t >> 6, lane = t & 63, quad = lane >> 4, lcol = lane & 15;
    int wr = w >> 1, wc = w & 1;

    floatx4 zero = {0.f, 0.f, 0.f, 0.f};
    floatx4 acc[4][4];
    #pragma unroll
    for (int i = 0; i < 4; ++i)
        #pragma unroll
        for (int j = 0; j < 4; ++j) acc[i][j] = zero;

    int sr = t >> 1;
    int sc = (t & 1) << 4;
    const unsigned short* aG = A + (size_t)(m0 + sr) * K + sc;
    const unsigned short* bG = Bt + (size_t)(n0 + sr) * K + sc;

    for (int k0 = 0; k0 < K; k0 += 32) {
        __syncthreads();
        *(int4*)(&As[sr * LDT + sc])     = *(const int4*)(aG + k0);
        *(int4*)(&As[sr * LDT + sc + 8]) = *(const int4*)(aG + k0 + 8);
        *(int4*)(&Bs[sr * LDT + sc])     = *(const int4*)(bG + k0);
        *(int4*)(&Bs[sr * LDT + sc + 8]) = *(const int4*)(bG + k0 + 8);
        __syncthreads();
        short8 af[4], bfm[4];
        #pragma unroll
        for (int i = 0; i < 4; ++i)
            af[i] = *(const short8*)(&As[(wr * 64 + i * 16 + lcol) * LDT + quad * 8]);
        #pragma unroll
        for (int j = 0; j < 4; ++j)
            bfm[j] = *(const short8*)(&Bs[(wc * 64 + j * 16 + lcol) * LDT + quad * 8]);
        #pragma unroll
        for (int i = 0; i < 4; ++i)
            #pragma unroll
            for (int j = 0; j < 4; ++j)
                acc[i][j] = __builtin_amdgcn_mfma_f32_16x16x32_bf16(af[i], bfm[j], acc[i][j], 0, 0, 0);
    }

    #pragma unroll
    for (int i = 0; i < 4; ++i) {
        int m = m0 + wr * 64 + i * 16 + quad * 4;
        #pragma unroll
        for (int j = 0; j < 4; ++j) {
            int n = n0 + wc * 64 + j * 16 + lcol;
            float bv = bias[n];
            #pragma unroll
            for (int r = 0; r < 4; ++r)
                Cout[(size_t)(m + r) * EMB + n] = acc[i][j][r] + bv;
        }
    }
}

// ---------------------------------------------------------------------------
extern "C" void kernel_launch(void* const* d_in, const int* in_sizes, int n_in,
                              void* d_out, int out_size, void* d_ws, size_t ws_size,
                              hipStream_t stream) {
    (void)in_sizes; (void)n_in; (void)out_size; (void)ws_size;
    char* ws = (char*)d_ws;
    const size_t OFF_X     = 0;                                      // 8 MB
    const size_t OFF_WQKVT = OFF_X     + (size_t)M_ROWS * EMB * 2;   // 6 MB
    const size_t OFF_WOT   = OFF_WQKVT + (size_t)N_QKV * EMB * 2;    // 2 MB
    const size_t OFF_Q     = OFF_WOT   + (size_t)EMB * EMB * 2;      // 8 MB
    const size_t OFF_K     = OFF_Q     + (size_t)M_ROWS * EMB * 2;
    const size_t OFF_V     = OFF_K     + (size_t)M_ROWS * EMB * 2;
    const size_t OFF_ATTN  = OFF_V     + (size_t)M_ROWS * EMB * 2;

    const float* x    = (const float*)d_in[0];
    const float* Wqkv = (const float*)d_in[1];
    const float* bqkv = (const float*)d_in[2];
    const float* Wo   = (const float*)d_in[3];
    const float* bo   = (const float*)d_in[4];

    unsigned short* x_bf  = (unsigned short*)(ws + OFF_X);
    unsigned short* wqkvT = (unsigned short*)(ws + OFF_WQKVT);
    unsigned short* woT   = (unsigned short*)(ws + OFF_WOT);
    unsigned short* qb    = (unsigned short*)(ws + OFF_Q);
    unsigned short* kb    = (unsigned short*)(ws + OFF_K);
    unsigned short* vb    = (unsigned short*)(ws + OFF_V);    // [B,H,D,S]
    unsigned short* attn  = (unsigned short*)(ws + OFF_ATTN);

    x_to_bf16<<<(M_ROWS * EMB / 4 + 255) / 256, 256, 0, stream>>>(x, x_bf, M_ROWS * EMB / 4);
    transpose_f32_bf16<<<dim3(N_QKV / 32, EMB / 32), dim3(32, 8), 0, stream>>>(Wqkv, wqkvT, EMB, N_QKV);
    transpose_f32_bf16<<<dim3(EMB / 32, EMB / 32), dim3(32, 8), 0, stream>>>(Wo, woT, EMB, EMB);

    qkv_gemm<<<dim3(N_QKV / 128, M_ROWS / 128), 256, 0, stream>>>(x_bf, wqkvT, bqkv, qb, kb, vb);
    attn_kernel<<<dim3(16, NB * NH), 256, 0, stream>>>(qb, kb, vb, attn);
    oproj_gemm<<<dim3(EMB / 128, M_ROWS / 128), 256, 0, stream>>>(attn, woT, bo, (float*)d_out);
}